// Round 5
// baseline (207.011 us; speedup 1.0000x reference)
//
#include <hip/hip_runtime.h>
#include <hip/hip_bf16.h>
#include <stdint.h>

#define DI __device__ __forceinline__

typedef float f32x4 __attribute__((ext_vector_type(4)));
typedef __bf16 bf16x8 __attribute__((ext_vector_type(8)));
typedef unsigned short ushort8v __attribute__((ext_vector_type(8)));

static constexpr int M = 1024;
static constexpr int N = 4096;
static constexpr int K = 4096;

// ---------------- fused fake-quant (f32, ref semantics) -> bf16 ----------------
DI unsigned short f2bf(float f) {
  union { __hip_bfloat16 h; unsigned short u; } cv;
  cv.h = __float2bfloat16(f);  // RNE
  return cv.u;
}

DI unsigned short fq1(float v, float s, float rs, float z) {
  float q = rintf(fmaf(v, rs, z));
  q = fminf(fmaxf(q, 0.0f), 255.0f);
  return f2bf((q - z) * s);
}

// x is written PACKED into MFMA A-fragment layout:
//   elem_off(t,kh,row,ks,e) = (t*2+kh)*32768 + (row>>4)*512 + ks*128 + (row&15)*8 + e
// (t = k-tile of 64, kh = k-half of 32, ks = 8-elem chunk, 8 elems per chunk)
// so a wave's A-frag load in the GEMM is base + lane*16B (fully coalesced).
// w is written linear [N][K] (staged to LDS by the GEMM).
static constexpr int NXP = M * K / 8;   // packed 8-elem chunks for x
static constexpr int N4W = N * K / 4;   // float4s for w

__global__ __launch_bounds__(256) void fq_kernel(
    const float* __restrict__ x, const float* __restrict__ wt,
    const float* __restrict__ a_scales, const float* __restrict__ a_zeros,
    const float* __restrict__ w_scales, const float* __restrict__ w_zeros,
    unsigned short* __restrict__ xqp, unsigned short* __restrict__ wq) {
  const int stride = gridDim.x * blockDim.x;
  for (int v = blockIdx.x * blockDim.x + threadIdx.x; v < NXP + N4W; v += stride) {
    if (v < NXP) {
      const int p   = v;
      const int fr  = p & 15;
      const int ks  = (p >> 4) & 3;
      const int rt  = (p >> 6) & 63;
      const int khh = (p >> 12) & 1;
      const int tk  = p >> 13;
      const int row = rt * 16 + fr;
      const int col = tk * 64 + khh * 32 + ks * 8;
      const float* src = x + (size_t)row * K + col;
      const float4 v0 = *(const float4*)src;
      const float4 v1 = *(const float4*)(src + 4);
      const int si = col >> 2;                    // a-scale idx (per 4 elems)
      const float s0 = a_scales[si],     z0 = a_zeros[si],     rs0 = 1.0f / s0;
      const float s1 = a_scales[si + 1], z1 = a_zeros[si + 1], rs1 = 1.0f / s1;
      ushort8v o;
      o[0] = fq1(v0.x, s0, rs0, z0); o[1] = fq1(v0.y, s0, rs0, z0);
      o[2] = fq1(v0.z, s0, rs0, z0); o[3] = fq1(v0.w, s0, rs0, z0);
      o[4] = fq1(v1.x, s1, rs1, z1); o[5] = fq1(v1.y, s1, rs1, z1);
      o[6] = fq1(v1.z, s1, rs1, z1); o[7] = fq1(v1.w, s1, rs1, z1);
      *(ushort8v*)(xqp + (size_t)p * 8) = o;     // 16B coalesced
    } else {
      const int q = v - NXP;
      const float s = w_scales[q], z = w_zeros[q], rs = 1.0f / s;
      const float4 t4 = reinterpret_cast<const float4*>(wt)[q];
      ushort4 o;
      o.x = fq1(t4.x, s, rs, z); o.y = fq1(t4.y, s, rs, z);
      o.z = fq1(t4.z, s, rs, z); o.w = fq1(t4.w, s, rs, z);
      reinterpret_cast<ushort4*>(wq)[q] = o;
    }
  }
}

// ---------------- bf16 GEMM: C[M,N] = A[M,K] * B[N,K]^T + bias ----------------
// 128x128 tile, 512 thr / 8 waves (2M x 2N x 2K-half). A read DIRECT from
// packed global (L1/L2-served, no LDS). B staged via global_load_lds into a
// 3-deep rotating swizzled buffer. One barrier per kstep; counted vmcnt.
static constexpr int BM = 128, BN = 128, BK = 64;
static constexpr int KT = K / BK;  // 64

DI void gl2lds16(const void* g, void* l) {
  __builtin_amdgcn_global_load_lds(
      (const __attribute__((address_space(1))) void*)g,
      (__attribute__((address_space(3))) void*)l, 16, 0, 0);
}

__global__ __launch_bounds__(512) void gemm_kernel(
    const unsigned short* __restrict__ Ap,   // packed A (fragment layout)
    const unsigned short* __restrict__ Bq,   // [N][K] bf16 bits
    const float* __restrict__ bias,
    float* __restrict__ C) {
  __shared__ char smem[65536];  // 3 x 16KB B bufs; reused as 64KB combine buf

  const int tid  = threadIdx.x;
  const int lane = tid & 63;
  const int w    = tid >> 6;        // 0..7
  const int kh   = w >> 2;          // k-half of each BK tile
  const int wq4  = w & 3;
  const int wm   = (wq4 >> 1) * 64;
  const int wn   = (wq4 & 1) * 64;
  const int fr   = lane & 15;

  // XCD swizzle: XCD x owns bn in {4x..4x+3} (B working set 4MB, L2-resident).
  const int xcd = blockIdx.x & 7;
  const int j   = blockIdx.x >> 3;
  const int bm  = (j & 7) * BM;
  const int bn  = (xcd * 4 + (j >> 3)) * BN;

  // --- B staging (wave-uniform LDS base + lane*16B; swizzle on global src) ---
  const int lrow = lane >> 3;                // == row&7
  const int scol = ((lane & 7) ^ lrow) * 8;  // pre-swizzled source col (elems)
  const unsigned short* gB0 = Bq + (size_t)(bn +      8 * w + lrow) * K + scol;
  const unsigned short* gB1 = Bq + (size_t)(bn + 64 + 8 * w + lrow) * K + scol;
  const int wofs = w * 1024;

  auto stage = [&](int k0, int s) {
    char* base = smem + s * 16384;
    gl2lds16(gB0 + k0, base + wofs);         // B rows  8w..8w+7
    gl2lds16(gB1 + k0, base + 8192 + wofs);  // B rows 64+8w..64+8w+7
  };

  // --- B fragment read offsets (swizzled) ---
  const int slot = kh * 4 + (lane >> 4);
  int boff[4];
#pragma unroll
  for (int f = 0; f < 4; ++f) {
    const int rb = wn + f * 16 + fr;
    boff[f] = rb * 64 + (slot ^ (rb & 7)) * 8;
  }

  // --- A packed-fragment base: frag(t, fm) = aBase + t*65536 + fm*512 ---
  const unsigned short* aBase = Ap + (size_t)kh * 32768 +
                                ((bm + wm) >> 4) * 512 +
                                (lane >> 4) * 128 + (lane & 15) * 8;

  f32x4 acc[4][4] = {};
  bf16x8 aA[4], aB[4];
  int cur = 0;  // LDS buffer holding tile t

  auto body = [&](int t, bf16x8 (&aCur)[4], bf16x8 (&aNxt)[4]) {
    if (t < KT - 1) asm volatile("s_waitcnt vmcnt(6)" ::: "memory");
    else            asm volatile("s_waitcnt vmcnt(4)" ::: "memory");
    __builtin_amdgcn_sched_barrier(0);
    __builtin_amdgcn_s_barrier();
    __builtin_amdgcn_sched_barrier(0);
    if (t + 2 < KT) {                    // stage into buf last read at t-1
      int nb = cur + 2; if (nb >= 3) nb -= 3;
      stage((t + 2) * BK, nb);
    }
    if (t + 1 < KT) {                    // A(t+1) -> alternate reg set
      const unsigned short* ap = aBase + (size_t)(t + 1) * 65536;
#pragma unroll
      for (int fm = 0; fm < 4; ++fm)
        aNxt[fm] = *(const bf16x8*)(ap + fm * 512);
    }
    const unsigned short* Bs = (const unsigned short*)(smem + cur * 16384);
    bf16x8 bF[4];
#pragma unroll
    for (int f = 0; f < 4; ++f) bF[f] = *(const bf16x8*)(Bs + boff[f]);
#pragma unroll
    for (int fm = 0; fm < 4; ++fm)
#pragma unroll
      for (int fn = 0; fn < 4; ++fn)
        acc[fm][fn] = __builtin_amdgcn_mfma_f32_16x16x32_bf16(aCur[fm], bF[fn], acc[fm][fn], 0, 0, 0);
    cur = (cur + 1 == 3) ? 0 : cur + 1;
  };

  // prologue: 2 B-tiles in flight + A(0) in regs
  stage(0, 0);
  stage(BK, 1);
#pragma unroll
  for (int fm = 0; fm < 4; ++fm)
    aA[fm] = *(const bf16x8*)(aBase + fm * 512);

  for (int t = 0; t < KT; t += 2) {  // KT even
    body(t,     aA, aB);
    body(t + 1, aB, aA);
  }

  // --- combine k-halves through LDS, add bias, store ---
  __syncthreads();
  float* cb = (float*)smem;  // [4 tiles][64 lanes][16 x f32x4], xor-swizzled
  if (kh == 1) {
#pragma unroll
    for (int fm = 0; fm < 4; ++fm)
#pragma unroll
      for (int fn = 0; fn < 4; ++fn) {
        const int sl = (fm * 4 + fn) ^ (lane & 15);
        *(f32x4*)(cb + ((wq4 * 64 + lane) * 16 + sl) * 4) = acc[fm][fn];
      }
  }
  __syncthreads();
  if (kh == 0) {
#pragma unroll
    for (int fm = 0; fm < 4; ++fm) {
#pragma unroll
      for (int fn = 0; fn < 4; ++fn) {
        const int sl = (fm * 4 + fn) ^ (lane & 15);
        f32x4 o = *(const f32x4*)(cb + ((wq4 * 64 + lane) * 16 + sl) * 4);
        o += acc[fm][fn];
        const int col = bn + wn + fn * 16 + fr;
        const float bv = bias[col];
        const int r0 = bm + wm + fm * 16 + ((lane >> 4) << 2);
#pragma unroll
        for (int r = 0; r < 4; ++r)
          C[(size_t)(r0 + r) * N + col] = o[r] + bv;
      }
    }
  }
}

extern "C" void kernel_launch(void* const* d_in, const int* in_sizes, int n_in,
                              void* d_out, int out_size, void* d_ws, size_t ws_size,
                              hipStream_t stream) {
  const float* x        = (const float*)d_in[0];
  const float* weight   = (const float*)d_in[1];
  const float* bias     = (const float*)d_in[2];
  const float* w_scales = (const float*)d_in[3];
  const float* w_zeros  = (const float*)d_in[4];
  const float* a_scales = (const float*)d_in[5];
  const float* a_zeros  = (const float*)d_in[6];
  float* out = (float*)d_out;

  unsigned short* xqp = (unsigned short*)d_ws;     // M*K bf16, packed
  unsigned short* wq  = xqp + (size_t)M * K;       // N*K bf16, linear

  fq_kernel<<<2048, 256, 0, stream>>>(x, weight, a_scales, a_zeros,
                                      w_scales, w_zeros, xqp, wq);
  gemm_kernel<<<(M / BM) * (N / BN), 512, 0, stream>>>(xqp, wq, bias, out);
}

// Round 6
// 203.019 us; speedup vs baseline: 1.0197x; 1.0197x over previous
//
#include <hip/hip_runtime.h>
#include <hip/hip_bf16.h>
#include <stdint.h>

#define DI __device__ __forceinline__

typedef float f32x4 __attribute__((ext_vector_type(4)));
typedef __bf16 bf16x8 __attribute__((ext_vector_type(8)));
typedef unsigned short ushort8v __attribute__((ext_vector_type(8)));

static constexpr int M = 1024;
static constexpr int N = 4096;
static constexpr int K = 4096;

// ---------------- fused fake-quant (f32, ref semantics) -> bf16 ----------------
DI unsigned short f2bf(float f) {
  union { __hip_bfloat16 h; unsigned short u; } cv;
  cv.h = __float2bfloat16(f);  // RNE
  return cv.u;
}

DI unsigned short fq1(float v, float s, float rs, float z) {
  float q = rintf(fmaf(v, rs, z));
  q = fminf(fmaxf(q, 0.0f), 255.0f);
  return f2bf((q - z) * s);
}

// x is written PACKED into MFMA A-fragment layout:
//   elem_off(t,kh,row,ks,e) = (t*2+kh)*32768 + (row>>4)*512 + ks*128 + (row&15)*8 + e
// so a wave's A-frag load in the GEMM is base + lane*16B (fully coalesced).
// w is written linear [N][K] (staged to LDS by the GEMM).
static constexpr int NXP = M * K / 8;   // packed 8-elem chunks for x
static constexpr int N4W = N * K / 4;   // float4s for w

__global__ __launch_bounds__(256) void fq_kernel(
    const float* __restrict__ x, const float* __restrict__ wt,
    const float* __restrict__ a_scales, const float* __restrict__ a_zeros,
    const float* __restrict__ w_scales, const float* __restrict__ w_zeros,
    unsigned short* __restrict__ xqp, unsigned short* __restrict__ wq) {
  const int stride = gridDim.x * blockDim.x;
  for (int v = blockIdx.x * blockDim.x + threadIdx.x; v < NXP + N4W; v += stride) {
    if (v < NXP) {
      const int p   = v;
      const int fr  = p & 15;
      const int ks  = (p >> 4) & 3;
      const int rt  = (p >> 6) & 63;
      const int khh = (p >> 12) & 1;
      const int tk  = p >> 13;
      const int row = rt * 16 + fr;
      const int col = tk * 64 + khh * 32 + ks * 8;
      const float* src = x + (size_t)row * K + col;
      const float4 v0 = *(const float4*)src;
      const float4 v1 = *(const float4*)(src + 4);
      const int si = col >> 2;                    // a-scale idx (per 4 elems)
      const float s0 = a_scales[si],     z0 = a_zeros[si],     rs0 = 1.0f / s0;
      const float s1 = a_scales[si + 1], z1 = a_zeros[si + 1], rs1 = 1.0f / s1;
      ushort8v o;
      o[0] = fq1(v0.x, s0, rs0, z0); o[1] = fq1(v0.y, s0, rs0, z0);
      o[2] = fq1(v0.z, s0, rs0, z0); o[3] = fq1(v0.w, s0, rs0, z0);
      o[4] = fq1(v1.x, s1, rs1, z1); o[5] = fq1(v1.y, s1, rs1, z1);
      o[6] = fq1(v1.z, s1, rs1, z1); o[7] = fq1(v1.w, s1, rs1, z1);
      *(ushort8v*)(xqp + (size_t)p * 8) = o;     // 16B coalesced
    } else {
      const int q = v - NXP;
      const float s = w_scales[q], z = w_zeros[q], rs = 1.0f / s;
      const float4 t4 = reinterpret_cast<const float4*>(wt)[q];
      ushort4 o;
      o.x = fq1(t4.x, s, rs, z); o.y = fq1(t4.y, s, rs, z);
      o.z = fq1(t4.z, s, rs, z); o.w = fq1(t4.w, s, rs, z);
      reinterpret_cast<ushort4*>(wq)[q] = o;
    }
  }
}

// ---------------- bf16 GEMM: C[M,N] = A[M,K] * B[N,K]^T + bias ----------------
// 128x128 tile, 512 thr / 8 waves (2M x 2N x 2K-half). A read DIRECT from
// packed global — XCD x owns bm=x, so A working set is 1MB/XCD = L2-resident.
// B staged via global_load_lds into a 3-deep rotating swizzled buffer.
// One barrier per kstep; counted vmcnt keeps stage(t+1),A(t+1),stage(t+2)
// in flight across the MFMA cluster.
static constexpr int BM = 128, BN = 128, BK = 64;
static constexpr int KT = K / BK;  // 64

DI void gl2lds16(const void* g, void* l) {
  __builtin_amdgcn_global_load_lds(
      (const __attribute__((address_space(1))) void*)g,
      (__attribute__((address_space(3))) void*)l, 16, 0, 0);
}

__global__ __launch_bounds__(512) void gemm_kernel(
    const unsigned short* __restrict__ Ap,   // packed A (fragment layout)
    const unsigned short* __restrict__ Bq,   // [N][K] bf16 bits
    const float* __restrict__ bias,
    float* __restrict__ C) {
  __shared__ char smem[65536];  // 3 x 16KB B bufs; reused as 64KB combine buf

  const int tid  = threadIdx.x;
  const int lane = tid & 63;
  const int w    = tid >> 6;        // 0..7
  const int kh   = w >> 2;          // k-half of each BK tile
  const int wq4  = w & 3;
  const int wm   = (wq4 >> 1) * 64;
  const int wn   = (wq4 & 1) * 64;
  const int fr   = lane & 15;

  // XCD mapping: block i -> XCD i&7 (round-robin). XCD x owns bm = x*128
  // (A slice 1MB, stays L2-resident) x all 32 bn (B streams per-kstep).
  const int bm = (blockIdx.x & 7) * BM;
  const int bn = (blockIdx.x >> 3) * BN;

  // --- B staging (wave-uniform LDS base + lane*16B; swizzle on global src) ---
  const int lrow = lane >> 3;                // == row&7
  const int scol = ((lane & 7) ^ lrow) * 8;  // pre-swizzled source col (elems)
  const unsigned short* gB0 = Bq + (size_t)(bn +      8 * w + lrow) * K + scol;
  const unsigned short* gB1 = Bq + (size_t)(bn + 64 + 8 * w + lrow) * K + scol;
  const int wofs = w * 1024;

  auto stage = [&](int k0, int s) {
    char* base = smem + s * 16384;
    gl2lds16(gB0 + k0, base + wofs);         // B rows  8w..8w+7
    gl2lds16(gB1 + k0, base + 8192 + wofs);  // B rows 64+8w..64+8w+7
  };

  // --- B fragment read offsets (swizzled) ---
  const int slot = kh * 4 + (lane >> 4);
  int boff[4];
#pragma unroll
  for (int f = 0; f < 4; ++f) {
    const int rb = wn + f * 16 + fr;
    boff[f] = rb * 64 + (slot ^ (rb & 7)) * 8;
  }

  // --- A packed-fragment base: frag(t, fm) = aBase + t*65536 + fm*512 ---
  const unsigned short* aBase = Ap + (size_t)kh * 32768 +
                                ((bm + wm) >> 4) * 512 +
                                (lane >> 4) * 128 + (lane & 15) * 8;

  f32x4 acc[4][4] = {};
  bf16x8 aA[4], aB[4];
  int cur = 0;  // LDS buffer holding tile t

  auto body = [&](int t, bf16x8 (&aCur)[4], bf16x8 (&aNxt)[4]) {
    // release exactly stage(t): newer ops = A(t)[4] + stage(t+1)[2]
    if (t < KT - 1) asm volatile("s_waitcnt vmcnt(6)" ::: "memory");
    else            asm volatile("s_waitcnt vmcnt(4)" ::: "memory");
    __builtin_amdgcn_sched_barrier(0);
    __builtin_amdgcn_s_barrier();
    __builtin_amdgcn_sched_barrier(0);
    if (t + 1 < KT) {                    // A(t+1) first (vmcnt accounting)
      const unsigned short* ap = aBase + (size_t)(t + 1) * 65536;
#pragma unroll
      for (int fm = 0; fm < 4; ++fm)
        aNxt[fm] = *(const bf16x8*)(ap + fm * 512);
    }
    if (t + 2 < KT) {                    // stage into buf last read at t-1
      int nb = cur + 2; if (nb >= 3) nb -= 3;
      stage((t + 2) * BK, nb);
    }
    const unsigned short* Bs = (const unsigned short*)(smem + cur * 16384);
    bf16x8 bF[4];
#pragma unroll
    for (int f = 0; f < 4; ++f) bF[f] = *(const bf16x8*)(Bs + boff[f]);
    __builtin_amdgcn_s_setprio(1);
#pragma unroll
    for (int fm = 0; fm < 4; ++fm)
#pragma unroll
      for (int fn = 0; fn < 4; ++fn)
        acc[fm][fn] = __builtin_amdgcn_mfma_f32_16x16x32_bf16(aCur[fm], bF[fn], acc[fm][fn], 0, 0, 0);
    __builtin_amdgcn_s_setprio(0);
    cur = (cur + 1 == 3) ? 0 : cur + 1;
  };

  // prologue: 2 B-tiles in flight + A(0) in regs
  stage(0, 0);
  stage(BK, 1);
#pragma unroll
  for (int fm = 0; fm < 4; ++fm)
    aA[fm] = *(const bf16x8*)(aBase + fm * 512);

  for (int t = 0; t < KT; t += 2) {  // KT even
    body(t,     aA, aB);
    body(t + 1, aB, aA);
  }

  // --- combine k-halves through LDS, add bias, store ---
  __syncthreads();
  float* cb = (float*)smem;  // [4 tiles][64 lanes][16 x f32x4], xor-swizzled
  if (kh == 1) {
#pragma unroll
    for (int fm = 0; fm < 4; ++fm)
#pragma unroll
      for (int fn = 0; fn < 4; ++fn) {
        const int sl = (fm * 4 + fn) ^ (lane & 15);
        *(f32x4*)(cb + ((wq4 * 64 + lane) * 16 + sl) * 4) = acc[fm][fn];
      }
  }
  __syncthreads();
  if (kh == 0) {
#pragma unroll
    for (int fm = 0; fm < 4; ++fm) {
#pragma unroll
      for (int fn = 0; fn < 4; ++fn) {
        const int sl = (fm * 4 + fn) ^ (lane & 15);
        f32x4 o = *(const f32x4*)(cb + ((wq4 * 64 + lane) * 16 + sl) * 4);
        o += acc[fm][fn];
        const int col = bn + wn + fn * 16 + fr;
        const float bv = bias[col];
        const int r0 = bm + wm + fm * 16 + ((lane >> 4) << 2);
#pragma unroll
        for (int r = 0; r < 4; ++r)
          C[(size_t)(r0 + r) * N + col] = o[r] + bv;
      }
    }
  }
}

extern "C" void kernel_launch(void* const* d_in, const int* in_sizes, int n_in,
                              void* d_out, int out_size, void* d_ws, size_t ws_size,
                              hipStream_t stream) {
  const float* x        = (const float*)d_in[0];
  const float* weight   = (const float*)d_in[1];
  const float* bias     = (const float*)d_in[2];
  const float* w_scales = (const float*)d_in[3];
  const float* w_zeros  = (const float*)d_in[4];
  const float* a_scales = (const float*)d_in[5];
  const float* a_zeros  = (const float*)d_in[6];
  float* out = (float*)d_out;

  unsigned short* xqp = (unsigned short*)d_ws;     // M*K bf16, packed
  unsigned short* wq  = xqp + (size_t)M * K;       // N*K bf16, linear

  fq_kernel<<<2048, 256, 0, stream>>>(x, weight, a_scales, a_zeros,
                                      w_scales, w_zeros, xqp, wq);
  gemm_kernel<<<(M / BM) * (N / BN), 512, 0, stream>>>(xqp, wq, bias, out);
}

// Round 7
// 201.600 us; speedup vs baseline: 1.0268x; 1.0070x over previous
//
#include <hip/hip_runtime.h>
#include <hip/hip_bf16.h>
#include <stdint.h>

#define DI __device__ __forceinline__

typedef float f32x4 __attribute__((ext_vector_type(4)));
typedef __bf16 bf16x8 __attribute__((ext_vector_type(8)));
typedef unsigned short ushort8v __attribute__((ext_vector_type(8)));

static constexpr int M = 1024;
static constexpr int N = 4096;
static constexpr int K = 4096;

// ---------------- fused fake-quant (f32, ref semantics) -> bf16 ----------------
DI unsigned short f2bf(float f) {
  union { __hip_bfloat16 h; unsigned short u; } cv;
  cv.h = __float2bfloat16(f);  // RNE
  return cv.u;
}

DI unsigned short fq1(float v, float s, float rs, float z) {
  float q = rintf(fmaf(v, rs, z));
  q = fminf(fmaxf(q, 0.0f), 255.0f);
  return f2bf((q - z) * s);
}

// x is written PACKED into MFMA A-fragment layout:
//   elem_off(t,kh,row,ks,e) = (t*2+kh)*32768 + (row>>4)*512 + ks*128 + (row&15)*8 + e
// so a wave's A-frag load in the GEMM is base + lane*16B (fully coalesced).
// w is written linear [N][K] (staged to LDS by the GEMM).
static constexpr int NXP = M * K / 8;   // packed 8-elem chunks for x
static constexpr int N4W = N * K / 4;   // float4s for w

__global__ __launch_bounds__(256) void fq_kernel(
    const float* __restrict__ x, const float* __restrict__ wt,
    const float* __restrict__ a_scales, const float* __restrict__ a_zeros,
    const float* __restrict__ w_scales, const float* __restrict__ w_zeros,
    unsigned short* __restrict__ xqp, unsigned short* __restrict__ wq) {
  const int stride = gridDim.x * blockDim.x;
  for (int v = blockIdx.x * blockDim.x + threadIdx.x; v < NXP + N4W; v += stride) {
    if (v < NXP) {
      const int p   = v;
      const int fr  = p & 15;
      const int ks  = (p >> 4) & 3;
      const int rt  = (p >> 6) & 63;
      const int khh = (p >> 12) & 1;
      const int tk  = p >> 13;
      const int row = rt * 16 + fr;
      const int col = tk * 64 + khh * 32 + ks * 8;
      const float* src = x + (size_t)row * K + col;
      const float4 v0 = *(const float4*)src;
      const float4 v1 = *(const float4*)(src + 4);
      const int si = col >> 2;                    // a-scale idx (per 4 elems)
      const float s0 = a_scales[si],     z0 = a_zeros[si],     rs0 = 1.0f / s0;
      const float s1 = a_scales[si + 1], z1 = a_zeros[si + 1], rs1 = 1.0f / s1;
      ushort8v o;
      o[0] = fq1(v0.x, s0, rs0, z0); o[1] = fq1(v0.y, s0, rs0, z0);
      o[2] = fq1(v0.z, s0, rs0, z0); o[3] = fq1(v0.w, s0, rs0, z0);
      o[4] = fq1(v1.x, s1, rs1, z1); o[5] = fq1(v1.y, s1, rs1, z1);
      o[6] = fq1(v1.z, s1, rs1, z1); o[7] = fq1(v1.w, s1, rs1, z1);
      *(ushort8v*)(xqp + (size_t)p * 8) = o;     // 16B coalesced
    } else {
      const int q = v - NXP;
      const float s = w_scales[q], z = w_zeros[q], rs = 1.0f / s;
      const float4 t4 = reinterpret_cast<const float4*>(wt)[q];
      ushort4 o;
      o.x = fq1(t4.x, s, rs, z); o.y = fq1(t4.y, s, rs, z);
      o.z = fq1(t4.z, s, rs, z); o.w = fq1(t4.w, s, rs, z);
      reinterpret_cast<ushort4*>(wq)[q] = o;
    }
  }
}

// ---------------- bf16 GEMM: C[M,N] = A[M,K] * B[N,K]^T + bias ----------------
// 128x128 tile, 512 thr / 8 waves (2M x 2N x 2K-half). B-panel L2-resident
// per XCD (xcd owns bn in {4x..4x+3} x all 8 bm -> 4MB, fetched once).
// A read DIRECT from packed global (k-slices stream L3->L2 at 1MB/kstep
// chip-wide; 2x wave-pair reuse via L1). B staged via global_load_lds into a
// 3-deep rotating swizzled buffer; one barrier per kstep; counted vmcnt.
static constexpr int BM = 128, BN = 128, BK = 64;
static constexpr int KT = K / BK;  // 64

DI void gl2lds16(const void* g, void* l) {
  __builtin_amdgcn_global_load_lds(
      (const __attribute__((address_space(1))) void*)g,
      (__attribute__((address_space(3))) void*)l, 16, 0, 0);
}

__global__ __launch_bounds__(512) void gemm_kernel(
    const unsigned short* __restrict__ Ap,   // packed A (fragment layout)
    const unsigned short* __restrict__ Bq,   // [N][K] bf16 bits
    const float* __restrict__ bias,
    float* __restrict__ C) {
  __shared__ char smem[65536];  // 3 x 16KB B bufs; reused as 64KB combine buf

  const int tid  = threadIdx.x;
  const int lane = tid & 63;
  const int w    = tid >> 6;        // 0..7
  const int kh   = w >> 2;          // k-half of each BK tile
  const int wq4  = w & 3;
  const int wm   = (wq4 >> 1) * 64;
  const int wn   = (wq4 & 1) * 64;
  const int fr   = lane & 15;

  // XCD mapping: block i -> XCD i&7. XCD x owns bn in {4x..4x+3} (B panel
  // 4MB = L2-resident, fetched once) x all 8 bm (A k-slices stream, 1MB/kstep
  // chip-wide from L3).
  const int xcd = blockIdx.x & 7;
  const int j   = blockIdx.x >> 3;          // 0..31
  const int bm  = (j & 7) * BM;
  const int bn  = (xcd * 4 + (j >> 3)) * BN;

  // --- B staging (wave-uniform LDS base + lane*16B; swizzle on global src) ---
  const int lrow = lane >> 3;                // == row&7
  const int scol = ((lane & 7) ^ lrow) * 8;  // pre-swizzled source col (elems)
  const unsigned short* gB0 = Bq + (size_t)(bn +      8 * w + lrow) * K + scol;
  const unsigned short* gB1 = Bq + (size_t)(bn + 64 + 8 * w + lrow) * K + scol;
  const int wofs = w * 1024;

  auto stage = [&](int k0, int s) {
    char* base = smem + s * 16384;
    gl2lds16(gB0 + k0, base + wofs);         // B rows  8w..8w+7
    gl2lds16(gB1 + k0, base + 8192 + wofs);  // B rows 64+8w..64+8w+7
  };

  // --- B fragment read offsets (swizzled) ---
  const int slot = kh * 4 + (lane >> 4);
  int boff[4];
#pragma unroll
  for (int f = 0; f < 4; ++f) {
    const int rb = wn + f * 16 + fr;
    boff[f] = rb * 64 + (slot ^ (rb & 7)) * 8;
  }

  // --- A packed-fragment base: frag(t, fm) = aBase + t*65536 + fm*512 ---
  const unsigned short* aBase = Ap + (size_t)kh * 32768 +
                                ((bm + wm) >> 4) * 512 +
                                (lane >> 4) * 128 + (lane & 15) * 8;

  f32x4 acc[4][4] = {};
  bf16x8 aA[4], aB[4];
  int cur = 0;  // LDS buffer holding tile t

  auto body = [&](int t, bf16x8 (&aCur)[4], bf16x8 (&aNxt)[4]) {
    // release exactly stage(t): newer ops = A(t)[4] + stage(t+1)[2]
    if (t < KT - 1) asm volatile("s_waitcnt vmcnt(6)" ::: "memory");
    else            asm volatile("s_waitcnt vmcnt(4)" ::: "memory");
    __builtin_amdgcn_sched_barrier(0);
    __builtin_amdgcn_s_barrier();
    __builtin_amdgcn_sched_barrier(0);
    if (t + 1 < KT) {                    // A(t+1) first (vmcnt accounting)
      const unsigned short* ap = aBase + (size_t)(t + 1) * 65536;
#pragma unroll
      for (int fm = 0; fm < 4; ++fm)
        aNxt[fm] = *(const bf16x8*)(ap + fm * 512);
    }
    if (t + 2 < KT) {                    // stage into buf last read at t-1
      int nb = cur + 2; if (nb >= 3) nb -= 3;
      stage((t + 2) * BK, nb);
    }
    const unsigned short* Bs = (const unsigned short*)(smem + cur * 16384);
    bf16x8 bF[4];
#pragma unroll
    for (int f = 0; f < 4; ++f) bF[f] = *(const bf16x8*)(Bs + boff[f]);
    __builtin_amdgcn_s_setprio(1);
#pragma unroll
    for (int fm = 0; fm < 4; ++fm)
#pragma unroll
      for (int fn = 0; fn < 4; ++fn)
        acc[fm][fn] = __builtin_amdgcn_mfma_f32_16x16x32_bf16(aCur[fm], bF[fn], acc[fm][fn], 0, 0, 0);
    __builtin_amdgcn_s_setprio(0);
    cur = (cur + 1 == 3) ? 0 : cur + 1;
  };

  // prologue: 2 B-tiles in flight + A(0) in regs
  stage(0, 0);
  stage(BK, 1);
#pragma unroll
  for (int fm = 0; fm < 4; ++fm)
    aA[fm] = *(const bf16x8*)(aBase + fm * 512);

  for (int t = 0; t < KT; t += 2) {  // KT even
    body(t,     aA, aB);
    body(t + 1, aB, aA);
  }

  // --- combine k-halves through LDS, add bias, store ---
  __syncthreads();
  float* cb = (float*)smem;  // [4 tiles][64 lanes][16 x f32x4], xor-swizzled
  if (kh == 1) {
#pragma unroll
    for (int fm = 0; fm < 4; ++fm)
#pragma unroll
      for (int fn = 0; fn < 4; ++fn) {
        const int sl = (fm * 4 + fn) ^ (lane & 15);
        *(f32x4*)(cb + ((wq4 * 64 + lane) * 16 + sl) * 4) = acc[fm][fn];
      }
  }
  __syncthreads();
  if (kh == 0) {
#pragma unroll
    for (int fm = 0; fm < 4; ++fm) {
#pragma unroll
      for (int fn = 0; fn < 4; ++fn) {
        const int sl = (fm * 4 + fn) ^ (lane & 15);
        f32x4 o = *(const f32x4*)(cb + ((wq4 * 64 + lane) * 16 + sl) * 4);
        o += acc[fm][fn];
        const int col = bn + wn + fn * 16 + fr;
        const float bv = bias[col];
        const int r0 = bm + wm + fm * 16 + ((lane >> 4) << 2);
#pragma unroll
        for (int r = 0; r < 4; ++r)
          C[(size_t)(r0 + r) * N + col] = o[r] + bv;
      }
    }
  }
}

extern "C" void kernel_launch(void* const* d_in, const int* in_sizes, int n_in,
                              void* d_out, int out_size, void* d_ws, size_t ws_size,
                              hipStream_t stream) {
  const float* x        = (const float*)d_in[0];
  const float* weight   = (const float*)d_in[1];
  const float* bias     = (const float*)d_in[2];
  const float* w_scales = (const float*)d_in[3];
  const float* w_zeros  = (const float*)d_in[4];
  const float* a_scales = (const float*)d_in[5];
  const float* a_zeros  = (const float*)d_in[6];
  float* out = (float*)d_out;

  unsigned short* xqp = (unsigned short*)d_ws;     // M*K bf16, packed
  unsigned short* wq  = xqp + (size_t)M * K;       // N*K bf16, linear

  fq_kernel<<<2048, 256, 0, stream>>>(x, weight, a_scales, a_zeros,
                                      w_scales, w_zeros, xqp, wq);
  gemm_kernel<<<(M / BM) * (N / BN), 512, 0, stream>>>(xqp, wq, bias, out);
}

// Round 8
// 192.944 us; speedup vs baseline: 1.0729x; 1.0449x over previous
//
#include <hip/hip_runtime.h>
#include <hip/hip_bf16.h>
#include <stdint.h>

#define DI __device__ __forceinline__

typedef float f32x4 __attribute__((ext_vector_type(4)));
typedef __bf16 bf16x8 __attribute__((ext_vector_type(8)));
typedef unsigned short ushort8v __attribute__((ext_vector_type(8)));

static constexpr int M = 1024;
static constexpr int N = 4096;
static constexpr int K = 4096;

// ---------------- fused fake-quant (f32, ref semantics) -> bf16 ----------------
DI unsigned short f2bf(float f) {
  union { __hip_bfloat16 h; unsigned short u; } cv;
  cv.h = __float2bfloat16(f);  // RNE
  return cv.u;
}

DI unsigned short fq1(float v, float s, float rs, float z) {
  float q = rintf(fmaf(v, rs, z));
  q = fminf(fmaxf(q, 0.0f), 255.0f);
  return f2bf((q - z) * s);
}

// x is written PACKED into MFMA A-fragment layout:
//   elem_off(t,kh,row,ks,e) = (t*2+kh)*32768 + (row>>4)*512 + ks*128 + (row&15)*8 + e
// so a wave's A-frag load in the GEMM is base + lane*16B (fully coalesced).
// w is written linear [N][K] (staged to LDS by the GEMM).
static constexpr int NXP = M * K / 8;   // packed 8-elem chunks for x
static constexpr int N4W = N * K / 4;   // float4s for w

__global__ __launch_bounds__(256) void fq_kernel(
    const float* __restrict__ x, const float* __restrict__ wt,
    const float* __restrict__ a_scales, const float* __restrict__ a_zeros,
    const float* __restrict__ w_scales, const float* __restrict__ w_zeros,
    unsigned short* __restrict__ xqp, unsigned short* __restrict__ wq) {
  const int stride = gridDim.x * blockDim.x;
  for (int v = blockIdx.x * blockDim.x + threadIdx.x; v < NXP + N4W; v += stride) {
    if (v < NXP) {
      const int p   = v;
      const int fr  = p & 15;
      const int ks  = (p >> 4) & 3;
      const int rt  = (p >> 6) & 63;
      const int khh = (p >> 12) & 1;
      const int tk  = p >> 13;
      const int row = rt * 16 + fr;
      const int col = tk * 64 + khh * 32 + ks * 8;
      const float* src = x + (size_t)row * K + col;
      const float4 v0 = *(const float4*)src;
      const float4 v1 = *(const float4*)(src + 4);
      const int si = col >> 2;                    // a-scale idx (per 4 elems)
      const float s0 = a_scales[si],     z0 = a_zeros[si],     rs0 = 1.0f / s0;
      const float s1 = a_scales[si + 1], z1 = a_zeros[si + 1], rs1 = 1.0f / s1;
      ushort8v o;
      o[0] = fq1(v0.x, s0, rs0, z0); o[1] = fq1(v0.y, s0, rs0, z0);
      o[2] = fq1(v0.z, s0, rs0, z0); o[3] = fq1(v0.w, s0, rs0, z0);
      o[4] = fq1(v1.x, s1, rs1, z1); o[5] = fq1(v1.y, s1, rs1, z1);
      o[6] = fq1(v1.z, s1, rs1, z1); o[7] = fq1(v1.w, s1, rs1, z1);
      *(ushort8v*)(xqp + (size_t)p * 8) = o;     // 16B coalesced
    } else {
      const int q = v - NXP;
      const float s = w_scales[q], z = w_zeros[q], rs = 1.0f / s;
      const float4 t4 = reinterpret_cast<const float4*>(wt)[q];
      ushort4 o;
      o.x = fq1(t4.x, s, rs, z); o.y = fq1(t4.y, s, rs, z);
      o.z = fq1(t4.z, s, rs, z); o.w = fq1(t4.w, s, rs, z);
      reinterpret_cast<ushort4*>(wq)[q] = o;
    }
  }
}

// ---------------- bf16 GEMM: C[M,N] = A[M,K] * B[N,K]^T + bias ----------------
// 128x64 tile, 256 thr / 4 waves (2M x 2K-half), TWO blocks per CU so the
// two barrier domains overlap each other's stalls. B-panel L2-resident per
// XCD (xcd owns 8 bn-tiles x all bm -> 4MB, fetched once). A read DIRECT
// from packed global. B staged via global_load_lds into a 3-deep rotating
// swizzled buffer; one barrier per kstep; counted vmcnt.
static constexpr int BM = 128, BN = 64, BK = 64;
static constexpr int KT = K / BK;  // 64

DI void gl2lds16(const void* g, void* l) {
  __builtin_amdgcn_global_load_lds(
      (const __attribute__((address_space(1))) void*)g,
      (__attribute__((address_space(3))) void*)l, 16, 0, 0);
}

__global__ __launch_bounds__(256, 2) void gemm_kernel(
    const unsigned short* __restrict__ Ap,   // packed A (fragment layout)
    const unsigned short* __restrict__ Bq,   // [N][K] bf16 bits
    const float* __restrict__ bias,
    float* __restrict__ C) {
  __shared__ char smem[32768];  // 3 x 8KB B bufs; reused as 32KB combine buf

  const int tid  = threadIdx.x;
  const int lane = tid & 63;
  const int w    = tid >> 6;        // 0..3
  const int kh   = w >> 1;          // k-half of each BK tile
  const int pid  = w & 1;           // m-half pair id
  const int wm   = pid * 64;
  const int fr   = lane & 15;

  // XCD mapping: block i -> XCD i&7. XCD x owns bn tiles {8x..8x+7}
  // (B panel 4MB = L2-resident, fetched once) x all 8 bm.
  const int xcd = blockIdx.x & 7;
  const int j   = blockIdx.x >> 3;          // 0..63
  const int bm  = (j & 7) * BM;
  const int bn  = (xcd * 8 + (j >> 3)) * BN;

  // --- B staging (wave-uniform LDS base + lane*16B; swizzle on global src) ---
  // Wave w covers rows 16w..16w+15 in two 1KB calls (8 rows each).
  const int lrow = lane >> 3;                // == row&7
  const int scol = ((lane & 7) ^ lrow) * 8;  // pre-swizzled source col (elems)
  const unsigned short* gB0 = Bq + (size_t)(bn + 16 * w + lrow) * K + scol;
  const unsigned short* gB1 = gB0 + (size_t)8 * K;
  const int wofs = w * 2048;

  auto stage = [&](int k0, int s) {
    char* base = smem + s * 8192;
    gl2lds16(gB0 + k0, base + wofs);          // rows 16w..16w+7
    gl2lds16(gB1 + k0, base + wofs + 1024);   // rows 16w+8..16w+15
  };

  // --- B fragment read offsets (swizzled) ---
  const int slot = kh * 4 + (lane >> 4);
  int boff[4];
#pragma unroll
  for (int f = 0; f < 4; ++f) {
    const int rb = f * 16 + fr;
    boff[f] = rb * 64 + (slot ^ (rb & 7)) * 8;
  }

  // --- A packed-fragment base: frag(t, fm) = aBase + t*65536 + fm*512 ---
  const unsigned short* aBase = Ap + (size_t)kh * 32768 +
                                ((bm + wm) >> 4) * 512 +
                                (lane >> 4) * 128 + (lane & 15) * 8;

  f32x4 acc[4][4] = {};
  bf16x8 aA[4], aB[4];
  int cur = 0;  // LDS buffer holding tile t

  auto body = [&](int t, bf16x8 (&aCur)[4], bf16x8 (&aNxt)[4]) {
    // release exactly stage(t): newer ops = A(t)[4] + stage(t+1)[2]
    if (t < KT - 1) asm volatile("s_waitcnt vmcnt(6)" ::: "memory");
    else            asm volatile("s_waitcnt vmcnt(4)" ::: "memory");
    __builtin_amdgcn_sched_barrier(0);
    __builtin_amdgcn_s_barrier();
    __builtin_amdgcn_sched_barrier(0);
    if (t + 1 < KT) {                    // A(t+1) first (vmcnt accounting)
      const unsigned short* ap = aBase + (size_t)(t + 1) * 65536;
#pragma unroll
      for (int fm = 0; fm < 4; ++fm)
        aNxt[fm] = *(const bf16x8*)(ap + fm * 512);
    }
    if (t + 2 < KT) {                    // stage into buf last read at t-1
      int nb = cur + 2; if (nb >= 3) nb -= 3;
      stage((t + 2) * BK, nb);
    }
    const unsigned short* Bs = (const unsigned short*)(smem + cur * 8192);
    bf16x8 bF[4];
#pragma unroll
    for (int f = 0; f < 4; ++f) bF[f] = *(const bf16x8*)(Bs + boff[f]);
    __builtin_amdgcn_s_setprio(1);
#pragma unroll
    for (int fm = 0; fm < 4; ++fm)
#pragma unroll
      for (int fn = 0; fn < 4; ++fn)
        acc[fm][fn] = __builtin_amdgcn_mfma_f32_16x16x32_bf16(aCur[fm], bF[fn], acc[fm][fn], 0, 0, 0);
    __builtin_amdgcn_s_setprio(0);
    cur = (cur + 1 == 3) ? 0 : cur + 1;
  };

  // prologue: 2 B-tiles in flight + A(0) in regs
  stage(0, 0);
  stage(BK, 1);
#pragma unroll
  for (int fm = 0; fm < 4; ++fm)
    aA[fm] = *(const bf16x8*)(aBase + fm * 512);

  for (int t = 0; t < KT; t += 2) {  // KT even
    body(t,     aA, aB);
    body(t + 1, aB, aA);
  }

  // --- combine k-halves through LDS, add bias, store ---
  __syncthreads();
  float* cb = (float*)smem;  // [2 pairs][64 lanes][16 x f32x4], xor-swizzled
  if (kh == 1) {
#pragma unroll
    for (int fm = 0; fm < 4; ++fm)
#pragma unroll
      for (int fn = 0; fn < 4; ++fn) {
        const int sl = (fm * 4 + fn) ^ (lane & 15);
        *(f32x4*)(cb + ((pid * 64 + lane) * 16 + sl) * 4) = acc[fm][fn];
      }
  }
  __syncthreads();
  if (kh == 0) {
#pragma unroll
    for (int fm = 0; fm < 4; ++fm) {
#pragma unroll
      for (int fn = 0; fn < 4; ++fn) {
        const int sl = (fm * 4 + fn) ^ (lane & 15);
        f32x4 o = *(const f32x4*)(cb + ((pid * 64 + lane) * 16 + sl) * 4);
        o += acc[fm][fn];
        const int col = bn + fn * 16 + fr;
        const float bv = bias[col];
        const int r0 = bm + wm + fm * 16 + ((lane >> 4) << 2);
#pragma unroll
        for (int r = 0; r < 4; ++r)
          C[(size_t)(r0 + r) * N + col] = o[r] + bv;
      }
    }
  }
}

extern "C" void kernel_launch(void* const* d_in, const int* in_sizes, int n_in,
                              void* d_out, int out_size, void* d_ws, size_t ws_size,
                              hipStream_t stream) {
  const float* x        = (const float*)d_in[0];
  const float* weight   = (const float*)d_in[1];
  const float* bias     = (const float*)d_in[2];
  const float* w_scales = (const float*)d_in[3];
  const float* w_zeros  = (const float*)d_in[4];
  const float* a_scales = (const float*)d_in[5];
  const float* a_zeros  = (const float*)d_in[6];
  float* out = (float*)d_out;

  unsigned short* xqp = (unsigned short*)d_ws;     // M*K bf16, packed
  unsigned short* wq  = xqp + (size_t)M * K;       // N*K bf16, linear

  fq_kernel<<<2048, 256, 0, stream>>>(x, weight, a_scales, a_zeros,
                                      w_scales, w_zeros, xqp, wq);
  gemm_kernel<<<(M / BM) * (N / BN), 256, 0, stream>>>(xqp, wq, bias, out);
}